// Round 15
// baseline (161.429 us; speedup 1.0000x reference)
//
#include <hip/hip_runtime.h>

// WaveNet single-output inference on MI355X — v9: best-known real path +
// 4 probe dispatches (dummy outputs) to separate chain-latency wall vs
// residency/shared-resource wall. Sparse tree: only skip_sum[:, :, 8190]
// matters; per-layer dependency positions form APs with stride dilation/2.
// PROBE template: 0 = real; 1 = no layer barriers; 2 = no sG LDS read
// (fragment built from own registers — wrong math, right shape).

typedef __attribute__((ext_vector_type(8))) short short8;
typedef __attribute__((ext_vector_type(4))) float f32x4;

#define TLAST 8190
#define BATCH 32
#define MFMA(A, B, C) __builtin_amdgcn_mfma_f32_16x16x32_bf16(A, B, C, 0, 0, 0)

__device__ __forceinline__ ushort bf16hi(float x) {
    union { float f; uint u; } v; v.f = x;
    return (ushort)((v.u + 0x7fffu + ((v.u >> 16) & 1u)) >> 16);
}
__device__ __forceinline__ uint packsplit(float v) {
    const ushort h = bf16hi(v);
    const float hf = __uint_as_float((uint)h << 16);
    return (uint)h | ((uint)bf16hi(v - hf) << 16);
}
__device__ __forceinline__ float unpacksum(uint u) {
    return __uint_as_float(u << 16) + __uint_as_float(u & 0xffff0000u);
}
__device__ __forceinline__ int imin(int a, int b) { return a < b ? a : b; }
__device__ __forceinline__ short8 mk8(uint a, uint b, uint c, uint d) {
    union { uint4 v; short8 s; } u; u.v = make_uint4(a, b, c, d); return u.s;
}
__device__ __forceinline__ void rdrow(const uint* p, short8& mh, short8& mc) {
    const uint4 q0 = *(const uint4*)p;
    const uint4 q1 = *(const uint4*)(p + 4);
    mh = mk8((q0.x & 0xffffu) | (q0.y << 16), (q0.z & 0xffffu) | (q0.w << 16),
             (q1.x & 0xffffu) | (q1.y << 16), (q1.z & 0xffffu) | (q1.w << 16));
    mc = mk8((q0.x >> 16) | (q0.y & 0xffff0000u), (q0.z >> 16) | (q0.w & 0xffff0000u),
             (q1.x >> 16) | (q1.y & 0xffff0000u), (q1.z >> 16) | (q1.w & 0xffff0000u));
}
__device__ __forceinline__ float act_native(float gate, float filt) {
    const float e1 = __builtin_amdgcn_exp2f(filt * 2.885390082f);
    const float th = 1.f - 2.f * __builtin_amdgcn_rcpf(e1 + 1.f);
    const float e2 = __builtin_amdgcn_exp2f(gate * -1.442695041f);
    return th * __builtin_amdgcn_rcpf(1.f + e2);
}

// ---------------------------------------------------------------- weight prep
__global__ __launch_bounds__(256) void wn_prep(
    const float* __restrict__ dil_w, const float* __restrict__ res_w,
    ushort* __restrict__ Wd, ushort* __restrict__ Wr)
{
    const int idx = blockIdx.x * 256 + threadIdx.x;
    if (idx < 12 * 4096) {
        const int l = idx >> 12, rem = idx & 4095, n = rem >> 6, k = rem & 63;
        const int kt = k >> 5, ic = k & 31, o = (k >> 3) & 3, r8 = k & 7;
        const int lane = o * 16 + (n & 15), nt = n >> 4;
        const float v = dil_w[((size_t)l * 64 + n) * 64 + 2 * ic + kt];
        const ushort h = bf16hi(v);
        const ushort lo = bf16hi(v - __uint_as_float((uint)h << 16));
        const int base = l * 8192 + ((kt * 4 + nt) * 2) * 512 + lane * 8 + r8;
        Wd[base] = h;
        Wd[base + 512] = lo;
    } else if (idx < 12 * 4096 + 12 * 1024) {
        const int j = idx - 12 * 4096;
        const int l = j >> 10, rem = j & 1023, n = rem >> 5, k = rem & 31;
        const int o = k >> 3, r8 = k & 7;
        const int lane = o * 16 + (n & 15), nt = n >> 4;
        const float v = res_w[j];
        const ushort h = bf16hi(v);
        const ushort lo = bf16hi(v - __uint_as_float((uint)h << 16));
        const int base = l * 2048 + (nt * 2) * 512 + lane * 8 + r8;
        Wr[base] = h;
        Wr[base + 512] = lo;
    }
}

// ---------------------------------------------------------------- phase A
// Block (4 waves) owns chunk cc = blockIdx.x (batch blockIdx.y); pyramid
// 96->95->47->23->11->5->2, tiles split across waves, 1 barrier/layer.
template<int PROBE>
__global__ __launch_bounds__(256) void wn_fuseA(
    const float* __restrict__ x, const float* __restrict__ in_w,
    const float* __restrict__ in_b,
    const ushort* __restrict__ Wd, const ushort* __restrict__ Wr,
    const float* __restrict__ dil_b, const float* __restrict__ res_b,
    uint* __restrict__ c6, float* __restrict__ gTL)
{
    __shared__ __align__(16) uint ping[96 * 36];
    __shared__ __align__(16) uint pong[95 * 36];
    __shared__ __align__(16) uint sG[4][16 * 36];
    float* xs = (float*)pong;

    const int tid = threadIdx.x, lane = tid & 63, w = tid >> 6;
    const int nl = lane & 15, o = lane >> 4;
    const int cc = blockIdx.x, b = blockIdx.y;
    const int t6a = 6174 + cc * 64, a0 = t6a - 31;
    const short8 z8 = {0, 0, 0, 0, 0, 0, 0, 0};

    for (int i = tid; i < 384; i += 256) {
        const int p = i >> 2, c4 = (i & 3) * 4;
        const int t = a0 + p;
        float4 v = make_float4(0.f, 0.f, 0.f, 0.f);
        if (t <= 8191) v = *(const float4*)&x[((size_t)b * 8192 + t) * 16 + c4];
        *(float4*)&xs[p * 20 + c4] = v;
    }
    __syncthreads();

    {
        const int c = tid & 31, pg = tid >> 5;
        float wr[16];
        #pragma unroll
        for (int f = 0; f < 16; ++f) wr[f] = in_w[c * 16 + f];
        const float bias = in_b[c];
        #pragma unroll
        for (int q = 0; q < 12; ++q) {
            const int p = pg + 8 * q;
            float acc = bias;
            #pragma unroll
            for (int f4 = 0; f4 < 4; ++f4) {
                const float4 xv = *(const float4*)&xs[p * 20 + f4 * 4];
                acc += wr[f4*4]*xv.x + wr[f4*4+1]*xv.y
                     + wr[f4*4+2]*xv.z + wr[f4*4+3]*xv.w;
            }
            ping[p * 36 + c] = packsplit(acc);
        }
    }
    __syncthreads();

    for (int l = 0; l < 6; ++l) {
        const uint* Hi = (l & 1) ? pong : ping;
        uint*       Ho = (l & 1) ? ping : pong;
        const int nIn  = (l == 0) ? 96 : (192 >> l) - 1;
        const int nOut = (192 >> (l + 1)) - 1;      // 95,47,23,11,5,2
        const int nT   = (nOut + 15) >> 4;
        const int sO   = 1 << l;
        const int aO   = a0 + sO - 1;
        const int bOff = (l == 0) ? 1 : (sO >> 1);
        const int rmx  = (l == 0) ? 8191 : TLAST;
        const int first = (l == 0);

        const ushort* pd = Wd + (size_t)l * 8192;
        const ushort* pr = Wr + (size_t)l * 2048;
        float dbg[2], dbf[2], rbv[2];
        #pragma unroll
        for (int nt = 0; nt < 2; ++nt) {
            dbg[nt] = dil_b[l * 64 + nl + 16 * nt];
            dbf[nt] = dil_b[l * 64 + nl + 16 * nt + 32];
            rbv[nt] = res_b[l * 32 + nl + 16 * nt];
        }

        for (int tt = w; tt < nT; tt += 4) {
            const int joF = tt * 16 + nl;
            const int j0 = imin(first ? joF : 2 * joF, nIn - 1);
            const int j1 = imin(first ? joF + 1 : 2 * joF + 2, nIn - 1);
            const bool zB = (aO + joF * sO + bOff) > rmx;

            short8 Ah[2], Al[2];
            rdrow(Hi + j0 * 36 + 8 * o, Ah[0], Al[0]);
            if (zB) { Ah[1] = z8; Al[1] = z8; }
            else    rdrow(Hi + j1 * 36 + 8 * o, Ah[1], Al[1]);

            f32x4 acc[4] = {{0,0,0,0},{0,0,0,0},{0,0,0,0},{0,0,0,0}};
            #pragma unroll
            for (int kt = 0; kt < 2; ++kt)
                #pragma unroll
                for (int nt = 0; nt < 4; ++nt) {
                    const int base = ((kt * 4 + nt) * 2) * 512 + lane * 8;
                    const short8 Bh = *(const short8*)&pd[base];
                    const short8 Bl = *(const short8*)&pd[base + 512];
                    acc[nt] = MFMA(Ah[kt], Bh, acc[nt]);
                    acc[nt] = MFMA(Ah[kt], Bl, acc[nt]);
                    acc[nt] = MFMA(Al[kt], Bh, acc[nt]);
                }

            uint pkv[8];
            #pragma unroll
            for (int nt = 0; nt < 2; ++nt)
                #pragma unroll
                for (int r = 0; r < 4; ++r) {
                    const float g = act_native(acc[nt][r] + dbg[nt],
                                               acc[nt + 2][r] + dbf[nt]);
                    const int ml = 4 * o + r, n = nl + 16 * nt;
                    const uint pk = packsplit(g);
                    pkv[nt * 4 + r] = pk;
                    sG[w][ml * 36 + n] = pk;
                    const int joG = tt * 16 + ml;
                    if (joG < nOut && (aO + joG * sO) == TLAST)
                        gTL[((size_t)l * BATCH + b) * 32 + n] = g;
                }

            short8 gh, gl;
            if (PROBE == 2) {
                // no LDS read-dependency: build fragment from own registers
                gh = mk8((pkv[0] & 0xffffu) | (pkv[1] << 16),
                         (pkv[2] & 0xffffu) | (pkv[3] << 16),
                         (pkv[4] & 0xffffu) | (pkv[5] << 16),
                         (pkv[6] & 0xffffu) | (pkv[7] << 16));
                gl = mk8((pkv[0] >> 16) | (pkv[1] & 0xffff0000u),
                         (pkv[2] >> 16) | (pkv[3] & 0xffff0000u),
                         (pkv[4] >> 16) | (pkv[5] & 0xffff0000u),
                         (pkv[6] >> 16) | (pkv[7] & 0xffff0000u));
            } else {
                rdrow(sG[w] + nl * 36 + 8 * o, gh, gl);
            }
            f32x4 aR[2] = {{0,0,0,0},{0,0,0,0}};
            #pragma unroll
            for (int nt = 0; nt < 2; ++nt) {
                const int base = (nt * 2) * 512 + lane * 8;
                const short8 Rh = *(const short8*)&pr[base];
                const short8 Rl = *(const short8*)&pr[base + 512];
                aR[nt] = MFMA(gh, Rh, aR[nt]);
                aR[nt] = MFMA(gh, Rl, aR[nt]);
                aR[nt] = MFMA(gl, Rh, aR[nt]);
            }
            #pragma unroll
            for (int nt = 0; nt < 2; ++nt)
                #pragma unroll
                for (int r = 0; r < 4; ++r) {
                    const int joE = tt * 16 + 4 * o + r;
                    if (joE < nOut) {
                        const int jres = imin(first ? joE + 1 : 2 * joE + 1, nIn - 1);
                        const int n = nl + 16 * nt;
                        const float resv = unpacksum(Hi[jres * 36 + n]);
                        const uint pk = packsplit(aR[nt][r] + rbv[nt] + resv);
                        Ho[joE * 36 + n] = pk;
                        if (l == 5 && joE < 2)
                            c6[((size_t)b * 64 + cc * 2 + joE) * 32 + n] = pk;
                    }
                }
        }
        if (PROBE != 1) __syncthreads();
    }
}

// ---------------------------------------------------------------- fuseB tile
__device__ __forceinline__ void layer_tile1(
    const uint* __restrict__ Hi, uint* __restrict__ Ho,
    const ushort* __restrict__ pd, const ushort* __restrict__ pr,
    const float* __restrict__ db, const float* __restrict__ rb,
    float* __restrict__ gout, uint* __restrict__ sG,
    int tt, int nIn, int nOut, int sO, int aO, int bOff,
    int lane, int nl, int o, int doRes)
{
    const short8 z8 = {0,0,0,0,0,0,0,0};
    const int joF = tt * 16 + nl;
    const int j0 = imin(2 * joF, nIn - 1);
    const int j1 = imin(2 * joF + 2, nIn - 1);
    const bool zB = (aO + joF * sO + bOff) > TLAST;

    short8 Ah[2], Al[2];
    rdrow(Hi + j0 * 36 + 8 * o, Ah[0], Al[0]);
    if (zB) { Ah[1] = z8; Al[1] = z8; }
    else    rdrow(Hi + j1 * 36 + 8 * o, Ah[1], Al[1]);

    f32x4 acc[4] = {{0,0,0,0},{0,0,0,0},{0,0,0,0},{0,0,0,0}};
    #pragma unroll
    for (int kt = 0; kt < 2; ++kt)
        #pragma unroll
        for (int nt = 0; nt < 4; ++nt) {
            const int base = ((kt * 4 + nt) * 2) * 512 + lane * 8;
            const short8 Bh = *(const short8*)&pd[base];
            const short8 Bl = *(const short8*)&pd[base + 512];
            acc[nt] = MFMA(Ah[kt], Bh, acc[nt]);
            acc[nt] = MFMA(Ah[kt], Bl, acc[nt]);
            acc[nt] = MFMA(Al[kt], Bh, acc[nt]);
        }

    float dbg[2], dbf[2], rbv[2];
    #pragma unroll
    for (int nt = 0; nt < 2; ++nt) {
        dbg[nt] = db[nl + 16 * nt];
        dbf[nt] = db[nl + 16 * nt + 32];
        rbv[nt] = rb[nl + 16 * nt];
    }

    #pragma unroll
    for (int nt = 0; nt < 2; ++nt)
        #pragma unroll
        for (int r = 0; r < 4; ++r) {
            const float g = act_native(acc[nt][r] + dbg[nt], acc[nt + 2][r] + dbf[nt]);
            const int ml = 4 * o + r, n = nl + 16 * nt;
            sG[ml * 36 + n] = packsplit(g);
            const int joG = tt * 16 + ml;
            if (joG < nOut && (aO + joG * sO) == TLAST) gout[n] = g;
        }

    if (doRes) {
        short8 gh, gl;
        rdrow(sG + nl * 36 + 8 * o, gh, gl);
        f32x4 aR[2] = {{0,0,0,0},{0,0,0,0}};
        #pragma unroll
        for (int nt = 0; nt < 2; ++nt) {
            const int base = (nt * 2) * 512 + lane * 8;
            const short8 Rh = *(const short8*)&pr[base];
            const short8 Rl = *(const short8*)&pr[base + 512];
            aR[nt] = MFMA(gh, Rh, aR[nt]);
            aR[nt] = MFMA(gh, Rl, aR[nt]);
            aR[nt] = MFMA(gl, Rh, aR[nt]);
        }
        #pragma unroll
        for (int nt = 0; nt < 2; ++nt)
            #pragma unroll
            for (int r = 0; r < 4; ++r) {
                const int joE = tt * 16 + 4 * o + r;
                if (joE < nOut) {
                    const int jres = imin(2 * joE + 1, nIn - 1);
                    const int n = nl + 16 * nt;
                    const float resv = unpacksum(Hi[jres * 36 + n]);
                    Ho[joE * 36 + n] = packsplit(aR[nt][r] + rbv[nt] + resv);
                }
            }
    }
}

// ---------------------------------------------------------------- phase B
__global__ __launch_bounds__(256) void wn_fuseB(
    const uint* __restrict__ c6,
    const ushort* __restrict__ Wd, const ushort* __restrict__ Wr,
    const float* __restrict__ dil_b, const float* __restrict__ res_b,
    const float* __restrict__ gTL,
    const float* __restrict__ sw, const float* __restrict__ sb,
    const float* __restrict__ f1w, const float* __restrict__ f1b,
    const float* __restrict__ f2w, const float* __restrict__ f2b,
    float* __restrict__ out)
{
    __shared__ __align__(16) uint HA[64 * 36];
    __shared__ __align__(16) uint HB[32 * 36];
    __shared__ __align__(16) uint sG2[2][16 * 36];
    __shared__ float gcap[6 * 32];
    __shared__ float psum[4][32];
    __shared__ float hd[64];

    const int tid = threadIdx.x, lane = tid & 63, w = tid >> 6;
    const int nl = lane & 15, o = lane >> 4;
    const int b = blockIdx.x;

    for (int i = tid; i < 512; i += 256) {
        const int row = i >> 3, c4 = (i & 7) * 4;
        *(uint4*)&HA[row * 36 + c4] = *(const uint4*)&c6[((size_t)b * 64 + row) * 32 + c4];
    }
    __syncthreads();

    if (w < 2) {
        layer_tile1(HA, HB, Wd + 6 * 8192, Wr + 6 * 2048,
                    dil_b + 6 * 64, res_b + 6 * 32,
                    gcap, sG2[w],
                    w, 64, 32, 64, 6206, 32, lane, nl, o, 1);
    }
    __syncthreads();

    if (w == 0) {
        for (int ll = 1; ll < 6; ++ll) {
            const int l = ll + 6;
            const uint* Hi = (ll & 1) ? HB : HA;
            uint*       Ho = (ll & 1) ? HA : HB;
            const int sO = 64 << ll;
            layer_tile1(Hi, Ho, Wd + (size_t)l * 8192, Wr + (size_t)l * 2048,
                        dil_b + l * 64, res_b + l * 32,
                        gcap + ll * 32, sG2[0],
                        0, 64 >> ll, 32 >> ll, sO, 6142 + sO, sO >> 1,
                        lane, nl, o, (ll < 5) ? 1 : 0);
        }
    }
    __syncthreads();

    if (lane < 32) {
        const int c = lane;
        float part = 0.f;
        #pragma unroll
        for (int j = 0; j < 3; ++j) {
            const int l2 = 3 * w + j;
            float a = sb[l2 * 32 + c];
            const float* swr = sw + l2 * 1024 + c * 32;
            const float* gv = (l2 < 6) ? (gTL + ((size_t)l2 * BATCH + b) * 32)
                                       : (gcap + (l2 - 6) * 32);
            #pragma unroll
            for (int ic = 0; ic < 32; ++ic) a += swr[ic] * gv[ic];
            part += a;
        }
        psum[w][c] = part;
    }
    __syncthreads();

    if (w == 0 && lane < 32)
        hd[lane] = fmaxf(psum[0][lane] + psum[1][lane] + psum[2][lane] + psum[3][lane], 0.f);
    if (w == 0 && lane < 32) {
        float z = f1b[lane];
        #pragma unroll
        for (int ic = 0; ic < 32; ++ic) z += f1w[lane * 32 + ic] * hd[ic];
        hd[32 + lane] = fmaxf(z, 0.f);
    }
    if (w == 0 && lane == 0) {
        float o2 = f2b[0];
        #pragma unroll
        for (int ic = 0; ic < 32; ++ic) o2 += f2w[ic] * hd[32 + ic];
        out[b] = o2;
    }
}

// ---------------------------------------------------------------- launch
extern "C" void kernel_launch(void* const* d_in, const int* in_sizes, int n_in,
                              void* d_out, int out_size, void* d_ws, size_t ws_size,
                              hipStream_t stream)
{
    const float* x      = (const float*)d_in[0];
    const float* in_w   = (const float*)d_in[1];
    const float* in_b   = (const float*)d_in[2];
    const float* dil_w  = (const float*)d_in[3];
    const float* dil_b  = (const float*)d_in[4];
    const float* skip_w = (const float*)d_in[5];
    const float* skip_b = (const float*)d_in[6];
    const float* res_w  = (const float*)d_in[7];
    const float* res_b  = (const float*)d_in[8];
    const float* f1_w   = (const float*)d_in[9];
    const float* f1_b   = (const float*)d_in[10];
    const float* f2_w   = (const float*)d_in[11];
    const float* f2_b   = (const float*)d_in[12];

    char* p = (char*)d_ws;
    ushort* Wd   = (ushort*)p; p += 12 * 8192 * 2;
    ushort* Wr   = (ushort*)p; p += 12 * 2048 * 2;
    uint*   c6   = (uint*)p;   p += 32 * 64 * 32 * 4;
    float*  gTL  = (float*)p;  p += 12 * 32 * 32 * 4;
    uint*   c6d  = (uint*)p;   p += 32 * 64 * 32 * 4;   // probe dummies
    float*  gTLd = (float*)p;

    wn_prep<<<dim3(240), dim3(256), 0, stream>>>(dil_w, res_w, Wd, Wr);

    // ---- real path
    wn_fuseA<0><<<dim3(32, BATCH), dim3(256), 0, stream>>>(
        x, in_w, in_b, Wd, Wr, dil_b, res_b, c6, gTL);
    wn_fuseB<<<dim3(BATCH), dim3(256), 0, stream>>>(
        c6, Wd, Wr, dil_b, res_b, gTL,
        skip_w, skip_b, f1_w, f1_b, f2_w, f2_b, (float*)d_out);

    // ---- probes (dummy outputs; read their dur in the rocprof table)
    // P1: single block -> pure block latency
    wn_fuseA<0><<<dim3(1, 1), dim3(256), 0, stream>>>(
        x, in_w, in_b, Wd, Wr, dil_b, res_b, c6d, gTLd);
    // P256: one block per CU -> latency w/o inter-block contention
    wn_fuseA<0><<<dim3(32, 8), dim3(256), 0, stream>>>(
        x, in_w, in_b, Wd, Wr, dil_b, res_b, c6d, gTLd);
    // P2: full grid, no layer barriers
    wn_fuseA<1><<<dim3(32, BATCH), dim3(256), 0, stream>>>(
        x, in_w, in_b, Wd, Wr, dil_b, res_b, c6d, gTLd);
    // P3: full grid, no sG LDS read-dependency
    wn_fuseA<2><<<dim3(32, BATCH), dim3(256), 0, stream>>>(
        x, in_w, in_b, Wd, Wr, dil_b, res_b, c6d, gTLd);
}

// Round 16
// 60.770 us; speedup vs baseline: 2.6564x; 2.6564x over previous
//
#include <hip/hip_runtime.h>
#include <hip/hip_bf16.h>

// WaveNet single-output inference on MI355X — v10: instruction-diet round.
// Sparse tree: only skip_sum[:, :, 8190] matters; per-layer dependency
// positions form APs with stride dilation/2; h_12 never needed.
// fuseA: block (4 waves) owns one chunk's in_conv + layers 0-5 pyramid
//        (96->95->47->23->11->5->2); tiles split across waves, 1 barrier/layer.
// fuseB: ll0 on 2 waves, ll1-5 wave 0, head split across 4 waves.
// v10 changes (all instruction-count cuts; indexing identical to r15-real):
//  - h stored as SEPARATE hi/lo bf16 LDS arrays -> MFMA fragments are direct
//    ds_read_b128 (removes 24 bit-ops x3 sites per tile; k-mapping unchanged,
//    weights untouched).
//  - bf16 converts via HW __float2bfloat16 (was 4-op manual RNE).
//  - act: tanh(f)*sig(g) = (e1-1)*rcp((e1+1)*(1+e2)), 2 exp2 + 1 rcp.
//  - gTL capture guarded by wave-uniform precheck (was 8 cmp/tile).

typedef __attribute__((ext_vector_type(8))) short short8;
typedef __attribute__((ext_vector_type(4))) float f32x4;

#define TLAST 8190
#define BATCH 32
#define MFMA(A, B, C) __builtin_amdgcn_mfma_f32_16x16x32_bf16(A, B, C, 0, 0, 0)

__device__ __forceinline__ ushort cvtb(float x) {
    union { __hip_bfloat16 b; ushort u; } c;
    c.b = __float2bfloat16(x);
    return c.u;
}
__device__ __forceinline__ float bf2f(ushort h) {
    return __uint_as_float((uint)h << 16);
}
__device__ __forceinline__ void split2(float v, ushort& h, ushort& l) {
    h = cvtb(v);
    l = cvtb(v - bf2f(h));
}
__device__ __forceinline__ int imin(int a, int b) { return a < b ? a : b; }
__device__ __forceinline__ float act_native(float gate, float filt) {
    const float e1 = __builtin_amdgcn_exp2f(filt * 2.885390082f);    // e^{2f}
    const float e2 = __builtin_amdgcn_exp2f(gate * -1.442695041f);   // e^{-g}
    return (e1 - 1.f) * __builtin_amdgcn_rcpf((e1 + 1.f) * (1.f + e2));
}

// ---------------------------------------------------------------- weight prep
// Frag-major bf16 (unchanged layout): dil k = ic + 32*kt, lane = o*16+nl,
// frag (a,kt,nt) at Wd[l*8192 + ((kt*4+nt)*2+a)*512 + lane*8 + (k&7)], a:0=h 1=lo.
__global__ __launch_bounds__(256) void wn_prep(
    const float* __restrict__ dil_w, const float* __restrict__ res_w,
    ushort* __restrict__ Wd, ushort* __restrict__ Wr)
{
    const int idx = blockIdx.x * 256 + threadIdx.x;
    if (idx < 12 * 4096) {
        const int l = idx >> 12, rem = idx & 4095, n = rem >> 6, k = rem & 63;
        const int kt = k >> 5, ic = k & 31, o = (k >> 3) & 3, r8 = k & 7;
        const int lane = o * 16 + (n & 15), nt = n >> 4;
        const float v = dil_w[((size_t)l * 64 + n) * 64 + 2 * ic + kt];
        ushort h, lo;
        split2(v, h, lo);
        const int base = l * 8192 + ((kt * 4 + nt) * 2) * 512 + lane * 8 + r8;
        Wd[base] = h;
        Wd[base + 512] = lo;
    } else if (idx < 12 * 4096 + 12 * 1024) {
        const int j = idx - 12 * 4096;
        const int l = j >> 10, rem = j & 1023, n = rem >> 5, k = rem & 31;
        const int o = k >> 3, r8 = k & 7;
        const int lane = o * 16 + (n & 15), nt = n >> 4;
        ushort h, lo;
        split2(res_w[j], h, lo);
        const int base = l * 2048 + (nt * 2) * 512 + lane * 8 + r8;
        Wr[base] = h;
        Wr[base + 512] = lo;
    }
}

// ---------------------------------------------------------------- phase A
// Grid (32, BATCH), 4 waves. Pyramid rows: stride 40 ushorts (80 B, 16B-aligned).
__global__ __launch_bounds__(256) void wn_fuseA(
    const float* __restrict__ x, const float* __restrict__ in_w,
    const float* __restrict__ in_b,
    const ushort* __restrict__ Wd, const ushort* __restrict__ Wr,
    const float* __restrict__ dil_b, const float* __restrict__ res_b,
    ushort* __restrict__ c6h, ushort* __restrict__ c6l,
    float* __restrict__ gTL)
{
    __shared__ __align__(16) ushort pingH[96 * 40], pingL[96 * 40];
    __shared__ __align__(16) ushort pongH[95 * 40], pongL[95 * 40];
    __shared__ __align__(16) ushort sGH[4][16 * 40], sGL[4][16 * 40];
    float* xs = (float*)pongH;                   // 96*20*4 = 7680 B, fits pongH

    const int tid = threadIdx.x, lane = tid & 63, w = tid >> 6;
    const int nl = lane & 15, o = lane >> 4;
    const int cc = blockIdx.x, b = blockIdx.y;
    const int t6a = 6174 + cc * 64, a0 = t6a - 31;
    const short8 z8 = {0, 0, 0, 0, 0, 0, 0, 0};

    // ---- stage x (96 pos x 16 ch fp32)
    for (int i = tid; i < 384; i += 256) {
        const int p = i >> 2, c4 = (i & 3) * 4;
        const int t = a0 + p;
        float4 v = make_float4(0.f, 0.f, 0.f, 0.f);
        if (t <= 8191) v = *(const float4*)&x[((size_t)b * 8192 + t) * 16 + c4];
        *(float4*)&xs[p * 20 + c4] = v;
    }
    __syncthreads();

    // ---- in_conv -> ping (hi/lo)
    {
        const int c = tid & 31, pg = tid >> 5;
        float wr[16];
        #pragma unroll
        for (int f = 0; f < 16; ++f) wr[f] = in_w[c * 16 + f];
        const float bias = in_b[c];
        #pragma unroll
        for (int q = 0; q < 12; ++q) {
            const int p = pg + 8 * q;
            float acc = bias;
            #pragma unroll
            for (int f4 = 0; f4 < 4; ++f4) {
                const float4 xv = *(const float4*)&xs[p * 20 + f4 * 4];
                acc += wr[f4*4]*xv.x + wr[f4*4+1]*xv.y
                     + wr[f4*4+2]*xv.z + wr[f4*4+3]*xv.w;
            }
            ushort hh, hl;
            split2(acc, hh, hl);
            pingH[p * 40 + c] = hh;
            pingL[p * 40 + c] = hl;
        }
    }
    __syncthreads();   // xs dead; pong free for l0 output

    for (int l = 0; l < 6; ++l) {
        const ushort* HiH = (l & 1) ? pongH : pingH;
        const ushort* HiL = (l & 1) ? pongL : pingL;
        ushort* HoH = (l & 1) ? pingH : pongH;
        ushort* HoL = (l & 1) ? pingL : pongL;
        const int nIn  = (l == 0) ? 96 : (192 >> l) - 1;
        const int nOut = (192 >> (l + 1)) - 1;      // 95,47,23,11,5,2
        const int nT   = (nOut + 15) >> 4;
        const int sO   = 1 << l;
        const int aO   = a0 + sO - 1;
        const int bOff = (l == 0) ? 1 : (sO >> 1);
        const int rmx  = (l == 0) ? 8191 : TLAST;
        const int first = (l == 0);
        // wave-uniform capture index for this layer (TLAST position)
        const int capRem = TLAST - aO;
        const int capIdx = ((capRem % sO) == 0) ? (capRem / sO) : -1;

        const ushort* pd = Wd + (size_t)l * 8192;
        const ushort* pr = Wr + (size_t)l * 2048;
        float dbg[2], dbf[2], rbv[2];
        #pragma unroll
        for (int nt = 0; nt < 2; ++nt) {
            dbg[nt] = dil_b[l * 64 + nl + 16 * nt];
            dbf[nt] = dil_b[l * 64 + nl + 16 * nt + 32];
            rbv[nt] = res_b[l * 32 + nl + 16 * nt];
        }

        for (int tt = w; tt < nT; tt += 4) {
            const int joF = tt * 16 + nl;
            const int j0 = imin(first ? joF : 2 * joF, nIn - 1);
            const int j1 = imin(first ? joF + 1 : 2 * joF + 2, nIn - 1);
            const bool zB = (aO + joF * sO + bOff) > rmx;

            short8 Ah[2], Al[2];
            Ah[0] = *(const short8*)&HiH[j0 * 40 + 8 * o];
            Al[0] = *(const short8*)&HiL[j0 * 40 + 8 * o];
            if (zB) { Ah[1] = z8; Al[1] = z8; }
            else {
                Ah[1] = *(const short8*)&HiH[j1 * 40 + 8 * o];
                Al[1] = *(const short8*)&HiL[j1 * 40 + 8 * o];
            }

            f32x4 acc[4] = {{0,0,0,0},{0,0,0,0},{0,0,0,0},{0,0,0,0}};
            #pragma unroll
            for (int kt = 0; kt < 2; ++kt)
                #pragma unroll
                for (int nt = 0; nt < 4; ++nt) {
                    const int base = ((kt * 4 + nt) * 2) * 512 + lane * 8;
                    const short8 Bh = *(const short8*)&pd[base];
                    const short8 Bl = *(const short8*)&pd[base + 512];
                    acc[nt] = MFMA(Ah[kt], Bh, acc[nt]);
                    acc[nt] = MFMA(Ah[kt], Bl, acc[nt]);
                    acc[nt] = MFMA(Al[kt], Bh, acc[nt]);
                }

            float gv[8];
            #pragma unroll
            for (int nt = 0; nt < 2; ++nt)
                #pragma unroll
                for (int r = 0; r < 4; ++r) {
                    const float g = act_native(acc[nt][r] + dbg[nt],
                                               acc[nt + 2][r] + dbf[nt]);
                    gv[nt * 4 + r] = g;
                    const int ml = 4 * o + r, n = nl + 16 * nt;
                    ushort gh16, gl16;
                    split2(g, gh16, gl16);
                    sGH[w][ml * 40 + n] = gh16;
                    sGL[w][ml * 40 + n] = gl16;
                }
            // rare wave-uniform capture
            if (capIdx >= tt * 16 && capIdx < imin(tt * 16 + 16, nOut)) {
                #pragma unroll
                for (int nt = 0; nt < 2; ++nt)
                    #pragma unroll
                    for (int r = 0; r < 4; ++r)
                        if (tt * 16 + 4 * o + r == capIdx)
                            gTL[((size_t)l * BATCH + b) * 32 + nl + 16 * nt] =
                                gv[nt * 4 + r];
            }

            const short8 gh = *(const short8*)&sGH[w][nl * 40 + 8 * o];
            const short8 gl = *(const short8*)&sGL[w][nl * 40 + 8 * o];
            f32x4 aR[2] = {{0,0,0,0},{0,0,0,0}};
            #pragma unroll
            for (int nt = 0; nt < 2; ++nt) {
                const int base = (nt * 2) * 512 + lane * 8;
                const short8 Rh = *(const short8*)&pr[base];
                const short8 Rl = *(const short8*)&pr[base + 512];
                aR[nt] = MFMA(gh, Rh, aR[nt]);
                aR[nt] = MFMA(gh, Rl, aR[nt]);
                aR[nt] = MFMA(gl, Rh, aR[nt]);
            }
            #pragma unroll
            for (int nt = 0; nt < 2; ++nt)
                #pragma unroll
                for (int r = 0; r < 4; ++r) {
                    const int joE = tt * 16 + 4 * o + r;
                    if (joE < nOut) {
                        const int jres = imin(first ? joE + 1 : 2 * joE + 1, nIn - 1);
                        const int n = nl + 16 * nt;
                        const float resv = bf2f(HiH[jres * 40 + n]) +
                                           bf2f(HiL[jres * 40 + n]);
                        ushort hh, hl;
                        split2(aR[nt][r] + rbv[nt] + resv, hh, hl);
                        HoH[joE * 40 + n] = hh;
                        HoL[joE * 40 + n] = hl;
                        if (l == 5 && joE < 2) {
                            const size_t go = ((size_t)b * 64 + cc * 2 + joE) * 32 + n;
                            c6h[go] = hh;
                            c6l[go] = hl;
                        }
                    }
                }
        }
        __syncthreads();
    }
}

// ---------------------------------------------------------------- fuseB tile
__device__ __forceinline__ void layer_tile1(
    const ushort* __restrict__ HiH, const ushort* __restrict__ HiL,
    ushort* __restrict__ HoH, ushort* __restrict__ HoL,
    const ushort* __restrict__ pd, const ushort* __restrict__ pr,
    const float* __restrict__ db, const float* __restrict__ rb,
    float* __restrict__ gout, ushort* __restrict__ sGH, ushort* __restrict__ sGL,
    int tt, int nIn, int nOut, int sO, int aO, int bOff,
    int lane, int nl, int o, int doRes)
{
    const short8 z8 = {0,0,0,0,0,0,0,0};
    const int joF = tt * 16 + nl;
    const int j0 = imin(2 * joF, nIn - 1);
    const int j1 = imin(2 * joF + 2, nIn - 1);
    const bool zB = (aO + joF * sO + bOff) > TLAST;

    short8 Ah[2], Al[2];
    Ah[0] = *(const short8*)&HiH[j0 * 40 + 8 * o];
    Al[0] = *(const short8*)&HiL[j0 * 40 + 8 * o];
    if (zB) { Ah[1] = z8; Al[1] = z8; }
    else {
        Ah[1] = *(const short8*)&HiH[j1 * 40 + 8 * o];
        Al[1] = *(const short8*)&HiL[j1 * 40 + 8 * o];
    }

    f32x4 acc[4] = {{0,0,0,0},{0,0,0,0},{0,0,0,0},{0,0,0,0}};
    #pragma unroll
    for (int kt = 0; kt < 2; ++kt)
        #pragma unroll
        for (int nt = 0; nt < 4; ++nt) {
            const int base = ((kt * 4 + nt) * 2) * 512 + lane * 8;
            const short8 Bh = *(const short8*)&pd[base];
            const short8 Bl = *(const short8*)&pd[base + 512];
            acc[nt] = MFMA(Ah[kt], Bh, acc[nt]);
            acc[nt] = MFMA(Ah[kt], Bl, acc[nt]);
            acc[nt] = MFMA(Al[kt], Bh, acc[nt]);
        }

    float dbg[2], dbf[2], rbv[2];
    #pragma unroll
    for (int nt = 0; nt < 2; ++nt) {
        dbg[nt] = db[nl + 16 * nt];
        dbf[nt] = db[nl + 16 * nt + 32];
        rbv[nt] = rb[nl + 16 * nt];
    }

    const int capRem = TLAST - aO;
    const int capIdx = ((capRem % sO) == 0) ? (capRem / sO) : -1;
    float gv[8];
    #pragma unroll
    for (int nt = 0; nt < 2; ++nt)
        #pragma unroll
        for (int r = 0; r < 4; ++r) {
            const float g = act_native(acc[nt][r] + dbg[nt], acc[nt + 2][r] + dbf[nt]);
            gv[nt * 4 + r] = g;
            const int ml = 4 * o + r, n = nl + 16 * nt;
            ushort gh16, gl16;
            split2(g, gh16, gl16);
            sGH[ml * 40 + n] = gh16;
            sGL[ml * 40 + n] = gl16;
        }
    if (capIdx >= tt * 16 && capIdx < imin(tt * 16 + 16, nOut)) {
        #pragma unroll
        for (int nt = 0; nt < 2; ++nt)
            #pragma unroll
            for (int r = 0; r < 4; ++r)
                if (tt * 16 + 4 * o + r == capIdx)
                    gout[nl + 16 * nt] = gv[nt * 4 + r];
    }

    if (doRes) {
        const short8 gh = *(const short8*)&sGH[nl * 40 + 8 * o];
        const short8 gl = *(const short8*)&sGL[nl * 40 + 8 * o];
        f32x4 aR[2] = {{0,0,0,0},{0,0,0,0}};
        #pragma unroll
        for (int nt = 0; nt < 2; ++nt) {
            const int base = (nt * 2) * 512 + lane * 8;
            const short8 Rh = *(const short8*)&pr[base];
            const short8 Rl = *(const short8*)&pr[base + 512];
            aR[nt] = MFMA(gh, Rh, aR[nt]);
            aR[nt] = MFMA(gh, Rl, aR[nt]);
            aR[nt] = MFMA(gl, Rh, aR[nt]);
        }
        #pragma unroll
        for (int nt = 0; nt < 2; ++nt)
            #pragma unroll
            for (int r = 0; r < 4; ++r) {
                const int joE = tt * 16 + 4 * o + r;
                if (joE < nOut) {
                    const int jres = imin(2 * joE + 1, nIn - 1);
                    const int n = nl + 16 * nt;
                    const float resv = bf2f(HiH[jres * 40 + n]) +
                                       bf2f(HiL[jres * 40 + n]);
                    ushort hh, hl;
                    split2(aR[nt][r] + rbv[nt] + resv, hh, hl);
                    HoH[joE * 40 + n] = hh;
                    HoL[joE * 40 + n] = hl;
                }
            }
    }
}

// ---------------------------------------------------------------- phase B
__global__ __launch_bounds__(256) void wn_fuseB(
    const ushort* __restrict__ c6h, const ushort* __restrict__ c6l,
    const ushort* __restrict__ Wd, const ushort* __restrict__ Wr,
    const float* __restrict__ dil_b, const float* __restrict__ res_b,
    const float* __restrict__ gTL,
    const float* __restrict__ sw, const float* __restrict__ sb,
    const float* __restrict__ f1w, const float* __restrict__ f1b,
    const float* __restrict__ f2w, const float* __restrict__ f2b,
    float* __restrict__ out)
{
    __shared__ __align__(16) ushort HAh[64 * 40], HAl[64 * 40];
    __shared__ __align__(16) ushort HBh[32 * 40], HBl[32 * 40];
    __shared__ __align__(16) ushort sG2H[2][16 * 40], sG2L[2][16 * 40];
    __shared__ float gcap[6 * 32];
    __shared__ float psum[4][32];
    __shared__ float hd[64];

    const int tid = threadIdx.x, lane = tid & 63, w = tid >> 6;
    const int nl = lane & 15, o = lane >> 4;
    const int b = blockIdx.x;

    // stage c6 (64 rows x 32 ch), short8 chunks
    for (int i = tid; i < 256; i += 256) {
        const int row = i >> 2, c8 = (i & 3) * 8;
        *(short8*)&HAh[row * 40 + c8] = *(const short8*)&c6h[((size_t)b * 64 + row) * 32 + c8];
        *(short8*)&HAl[row * 40 + c8] = *(const short8*)&c6l[((size_t)b * 64 + row) * 32 + c8];
    }
    __syncthreads();

    if (w < 2) {
        layer_tile1(HAh, HAl, HBh, HBl, Wd + 6 * 8192, Wr + 6 * 2048,
                    dil_b + 6 * 64, res_b + 6 * 32,
                    gcap, sG2H[w], sG2L[w],
                    w, 64, 32, 64, 6206, 32, lane, nl, o, 1);
    }
    __syncthreads();

    if (w == 0) {
        for (int ll = 1; ll < 6; ++ll) {
            const int l = ll + 6;
            const ushort* HiH = (ll & 1) ? HBh : HAh;
            const ushort* HiL = (ll & 1) ? HBl : HAl;
            ushort* HoH = (ll & 1) ? HAh : HBh;
            ushort* HoL = (ll & 1) ? HAl : HBl;
            const int sO = 64 << ll;
            layer_tile1(HiH, HiL, HoH, HoL,
                        Wd + (size_t)l * 8192, Wr + (size_t)l * 2048,
                        dil_b + l * 64, res_b + l * 32,
                        gcap + ll * 32, sG2H[0], sG2L[0],
                        0, 64 >> ll, 32 >> ll, sO, 6142 + sO, sO >> 1,
                        lane, nl, o, (ll < 5) ? 1 : 0);
        }
    }
    __syncthreads();

    if (lane < 32) {
        const int c = lane;
        float part = 0.f;
        #pragma unroll
        for (int j = 0; j < 3; ++j) {
            const int l2 = 3 * w + j;
            float a = sb[l2 * 32 + c];
            const float* swr = sw + l2 * 1024 + c * 32;
            const float* gvp = (l2 < 6) ? (gTL + ((size_t)l2 * BATCH + b) * 32)
                                        : (gcap + (l2 - 6) * 32);
            #pragma unroll
            for (int ic = 0; ic < 32; ++ic) a += swr[ic] * gvp[ic];
            part += a;
        }
        psum[w][c] = part;
    }
    __syncthreads();

    if (w == 0 && lane < 32)
        hd[lane] = fmaxf(psum[0][lane] + psum[1][lane] + psum[2][lane] + psum[3][lane], 0.f);
    if (w == 0 && lane < 32) {
        float z = f1b[lane];
        #pragma unroll
        for (int ic = 0; ic < 32; ++ic) z += f1w[lane * 32 + ic] * hd[ic];
        hd[32 + lane] = fmaxf(z, 0.f);
    }
    if (w == 0 && lane == 0) {
        float o2 = f2b[0];
        #pragma unroll
        for (int ic = 0; ic < 32; ++ic) o2 += f2w[ic] * hd[32 + ic];
        out[b] = o2;
    }
}

// ---------------------------------------------------------------- launch
extern "C" void kernel_launch(void* const* d_in, const int* in_sizes, int n_in,
                              void* d_out, int out_size, void* d_ws, size_t ws_size,
                              hipStream_t stream)
{
    const float* x      = (const float*)d_in[0];
    const float* in_w   = (const float*)d_in[1];
    const float* in_b   = (const float*)d_in[2];
    const float* dil_w  = (const float*)d_in[3];
    const float* dil_b  = (const float*)d_in[4];
    const float* skip_w = (const float*)d_in[5];
    const float* skip_b = (const float*)d_in[6];
    const float* res_w  = (const float*)d_in[7];
    const float* res_b  = (const float*)d_in[8];
    const float* f1_w   = (const float*)d_in[9];
    const float* f1_b   = (const float*)d_in[10];
    const float* f2_w   = (const float*)d_in[11];
    const float* f2_b   = (const float*)d_in[12];

    char* p = (char*)d_ws;
    ushort* Wd  = (ushort*)p; p += 12 * 8192 * 2;
    ushort* Wr  = (ushort*)p; p += 12 * 2048 * 2;
    ushort* c6h = (ushort*)p; p += 32 * 64 * 32 * 2;
    ushort* c6l = (ushort*)p; p += 32 * 64 * 32 * 2;
    float*  gTL = (float*)p;

    wn_prep<<<dim3(240), dim3(256), 0, stream>>>(dil_w, res_w, Wd, Wr);

    wn_fuseA<<<dim3(32, BATCH), dim3(256), 0, stream>>>(
        x, in_w, in_b, Wd, Wr, dil_b, res_b, c6h, c6l, gTL);

    wn_fuseB<<<dim3(BATCH), dim3(256), 0, stream>>>(
        c6h, c6l, Wd, Wr, dil_b, res_b, gTL,
        skip_w, skip_b, f1_w, f1_b, f2_w, f2_b, (float*)d_out);
}

// Round 17
// 59.011 us; speedup vs baseline: 2.7356x; 1.0298x over previous
//
#include <hip/hip_runtime.h>
#include <hip/hip_bf16.h>

// WaveNet single-output inference on MI355X — v11: C-init diet.
// Sparse tree: only skip_sum[:, :, 8190] matters; per-layer dependency
// positions form APs with stride dilation/2; h_12 never needed.
// fuseA: block (4 waves) owns one chunk's in_conv + layers 0-5 pyramid
//        (96->95->47->23->11->5->2); tiles split across waves, 1 barrier/layer.
// fuseB: ll0 on 2 waves, ll1-5 wave 0, head split across 4 waves.
// v11 changes vs r16 (both kernels; indexing identical):
//  - gate/filt bias folded into MFMA accumulator init (C-operand), not added after.
//  - residual taps read at tile top and folded into res-GEMM accumulator init
//    (reads overlap the 24-MFMA gate block; post-adds eliminated).
//  - epilogue stores split2(accR) directly.

typedef __attribute__((ext_vector_type(8))) short short8;
typedef __attribute__((ext_vector_type(4))) float f32x4;

#define TLAST 8190
#define BATCH 32
#define MFMA(A, B, C) __builtin_amdgcn_mfma_f32_16x16x32_bf16(A, B, C, 0, 0, 0)

__device__ __forceinline__ ushort cvtb(float x) {
    union { __hip_bfloat16 b; ushort u; } c;
    c.b = __float2bfloat16(x);
    return c.u;
}
__device__ __forceinline__ float bf2f(ushort h) {
    return __uint_as_float((uint)h << 16);
}
__device__ __forceinline__ void split2(float v, ushort& h, ushort& l) {
    h = cvtb(v);
    l = cvtb(v - bf2f(h));
}
__device__ __forceinline__ int imin(int a, int b) { return a < b ? a : b; }
__device__ __forceinline__ float act_native(float gate, float filt) {
    const float e1 = __builtin_amdgcn_exp2f(filt * 2.885390082f);    // e^{2f}
    const float e2 = __builtin_amdgcn_exp2f(gate * -1.442695041f);   // e^{-g}
    return (e1 - 1.f) * __builtin_amdgcn_rcpf((e1 + 1.f) * (1.f + e2));
}

// ---------------------------------------------------------------- weight prep
// Frag-major bf16: dil k = ic + 32*kt, lane = o*16+nl,
// frag (a,kt,nt) at Wd[l*8192 + ((kt*4+nt)*2+a)*512 + lane*8 + (k&7)], a:0=h 1=lo.
__global__ __launch_bounds__(256) void wn_prep(
    const float* __restrict__ dil_w, const float* __restrict__ res_w,
    ushort* __restrict__ Wd, ushort* __restrict__ Wr)
{
    const int idx = blockIdx.x * 256 + threadIdx.x;
    if (idx < 12 * 4096) {
        const int l = idx >> 12, rem = idx & 4095, n = rem >> 6, k = rem & 63;
        const int kt = k >> 5, ic = k & 31, o = (k >> 3) & 3, r8 = k & 7;
        const int lane = o * 16 + (n & 15), nt = n >> 4;
        const float v = dil_w[((size_t)l * 64 + n) * 64 + 2 * ic + kt];
        ushort h, lo;
        split2(v, h, lo);
        const int base = l * 8192 + ((kt * 4 + nt) * 2) * 512 + lane * 8 + r8;
        Wd[base] = h;
        Wd[base + 512] = lo;
    } else if (idx < 12 * 4096 + 12 * 1024) {
        const int j = idx - 12 * 4096;
        const int l = j >> 10, rem = j & 1023, n = rem >> 5, k = rem & 31;
        const int o = k >> 3, r8 = k & 7;
        const int lane = o * 16 + (n & 15), nt = n >> 4;
        ushort h, lo;
        split2(res_w[j], h, lo);
        const int base = l * 2048 + (nt * 2) * 512 + lane * 8 + r8;
        Wr[base] = h;
        Wr[base + 512] = lo;
    }
}

// ---------------------------------------------------------------- phase A
// Grid (32, BATCH), 4 waves. Pyramid rows: stride 40 ushorts (80 B).
__global__ __launch_bounds__(256) void wn_fuseA(
    const float* __restrict__ x, const float* __restrict__ in_w,
    const float* __restrict__ in_b,
    const ushort* __restrict__ Wd, const ushort* __restrict__ Wr,
    const float* __restrict__ dil_b, const float* __restrict__ res_b,
    ushort* __restrict__ c6h, ushort* __restrict__ c6l,
    float* __restrict__ gTL)
{
    __shared__ __align__(16) ushort pingH[96 * 40], pingL[96 * 40];
    __shared__ __align__(16) ushort pongH[95 * 40], pongL[95 * 40];
    __shared__ __align__(16) ushort sGH[4][16 * 40], sGL[4][16 * 40];
    float* xs = (float*)pongH;                   // 7680 B, fits pongH

    const int tid = threadIdx.x, lane = tid & 63, w = tid >> 6;
    const int nl = lane & 15, o = lane >> 4;
    const int cc = blockIdx.x, b = blockIdx.y;
    const int t6a = 6174 + cc * 64, a0 = t6a - 31;
    const short8 z8 = {0, 0, 0, 0, 0, 0, 0, 0};

    // ---- stage x (96 pos x 16 ch fp32)
    for (int i = tid; i < 384; i += 256) {
        const int p = i >> 2, c4 = (i & 3) * 4;
        const int t = a0 + p;
        float4 v = make_float4(0.f, 0.f, 0.f, 0.f);
        if (t <= 8191) v = *(const float4*)&x[((size_t)b * 8192 + t) * 16 + c4];
        *(float4*)&xs[p * 20 + c4] = v;
    }
    __syncthreads();

    // ---- in_conv -> ping (hi/lo)
    {
        const int c = tid & 31, pg = tid >> 5;
        float wr[16];
        #pragma unroll
        for (int f = 0; f < 16; ++f) wr[f] = in_w[c * 16 + f];
        const float bias = in_b[c];
        #pragma unroll
        for (int q = 0; q < 12; ++q) {
            const int p = pg + 8 * q;
            float acc = bias;
            #pragma unroll
            for (int f4 = 0; f4 < 4; ++f4) {
                const float4 xv = *(const float4*)&xs[p * 20 + f4 * 4];
                acc += wr[f4*4]*xv.x + wr[f4*4+1]*xv.y
                     + wr[f4*4+2]*xv.z + wr[f4*4+3]*xv.w;
            }
            ushort hh, hl;
            split2(acc, hh, hl);
            pingH[p * 40 + c] = hh;
            pingL[p * 40 + c] = hl;
        }
    }
    __syncthreads();   // xs dead; pong free for l0 output

    for (int l = 0; l < 6; ++l) {
        const ushort* HiH = (l & 1) ? pongH : pingH;
        const ushort* HiL = (l & 1) ? pongL : pingL;
        ushort* HoH = (l & 1) ? pingH : pongH;
        ushort* HoL = (l & 1) ? pingL : pongL;
        const int nIn  = (l == 0) ? 96 : (192 >> l) - 1;
        const int nOut = (192 >> (l + 1)) - 1;      // 95,47,23,11,5,2
        const int nT   = (nOut + 15) >> 4;
        const int sO   = 1 << l;
        const int aO   = a0 + sO - 1;
        const int bOff = (l == 0) ? 1 : (sO >> 1);
        const int rmx  = (l == 0) ? 8191 : TLAST;
        const int first = (l == 0);
        const int capRem = TLAST - aO;
        const int capIdx = ((capRem % sO) == 0) ? (capRem / sO) : -1;

        const ushort* pd = Wd + (size_t)l * 8192;
        const ushort* pr = Wr + (size_t)l * 2048;
        float dbg[2], dbf[2], rbv[2];
        #pragma unroll
        for (int nt = 0; nt < 2; ++nt) {
            dbg[nt] = dil_b[l * 64 + nl + 16 * nt];
            dbf[nt] = dil_b[l * 64 + nl + 16 * nt + 32];
            rbv[nt] = res_b[l * 32 + nl + 16 * nt];
        }

        for (int tt = w; tt < nT; tt += 4) {
            const int joF = tt * 16 + nl;
            const int j0 = imin(first ? joF : 2 * joF, nIn - 1);
            const int j1 = imin(first ? joF + 1 : 2 * joF + 2, nIn - 1);
            const bool zB = (aO + joF * sO + bOff) > rmx;

            // ---- residual taps first (independent; overlap gate GEMM)
            f32x4 aR[2];
            #pragma unroll
            for (int nt = 0; nt < 2; ++nt)
                #pragma unroll
                for (int r = 0; r < 4; ++r) {
                    const int joE = tt * 16 + 4 * o + r;
                    const int jres = imin(first ? joE + 1 : 2 * joE + 1, nIn - 1);
                    const int n = nl + 16 * nt;
                    aR[nt][r] = rbv[nt] + bf2f(HiH[jres * 40 + n]) +
                                bf2f(HiL[jres * 40 + n]);
                }

            short8 Ah[2], Al[2];
            Ah[0] = *(const short8*)&HiH[j0 * 40 + 8 * o];
            Al[0] = *(const short8*)&HiL[j0 * 40 + 8 * o];
            if (zB) { Ah[1] = z8; Al[1] = z8; }
            else {
                Ah[1] = *(const short8*)&HiH[j1 * 40 + 8 * o];
                Al[1] = *(const short8*)&HiL[j1 * 40 + 8 * o];
            }

            // ---- gate/filt GEMM, bias in C-init
            f32x4 acc[4];
            #pragma unroll
            for (int nt = 0; nt < 2; ++nt) {
                acc[nt]     = (f32x4){dbg[nt], dbg[nt], dbg[nt], dbg[nt]};
                acc[nt + 2] = (f32x4){dbf[nt], dbf[nt], dbf[nt], dbf[nt]};
            }
            #pragma unroll
            for (int kt = 0; kt < 2; ++kt)
                #pragma unroll
                for (int nt = 0; nt < 4; ++nt) {
                    const int base = ((kt * 4 + nt) * 2) * 512 + lane * 8;
                    const short8 Bh = *(const short8*)&pd[base];
                    const short8 Bl = *(const short8*)&pd[base + 512];
                    acc[nt] = MFMA(Ah[kt], Bh, acc[nt]);
                    acc[nt] = MFMA(Ah[kt], Bl, acc[nt]);
                    acc[nt] = MFMA(Al[kt], Bh, acc[nt]);
                }

            float gv[8];
            #pragma unroll
            for (int nt = 0; nt < 2; ++nt)
                #pragma unroll
                for (int r = 0; r < 4; ++r) {
                    const float g = act_native(acc[nt][r], acc[nt + 2][r]);
                    gv[nt * 4 + r] = g;
                    const int ml = 4 * o + r, n = nl + 16 * nt;
                    ushort gh16, gl16;
                    split2(g, gh16, gl16);
                    sGH[w][ml * 40 + n] = gh16;
                    sGL[w][ml * 40 + n] = gl16;
                }
            if (capIdx >= tt * 16 && capIdx < imin(tt * 16 + 16, nOut)) {
                #pragma unroll
                for (int nt = 0; nt < 2; ++nt)
                    #pragma unroll
                    for (int r = 0; r < 4; ++r)
                        if (tt * 16 + 4 * o + r == capIdx)
                            gTL[((size_t)l * BATCH + b) * 32 + nl + 16 * nt] =
                                gv[nt * 4 + r];
            }

            // ---- res GEMM, residual+bias in C-init
            const short8 gh = *(const short8*)&sGH[w][nl * 40 + 8 * o];
            const short8 gl = *(const short8*)&sGL[w][nl * 40 + 8 * o];
            #pragma unroll
            for (int nt = 0; nt < 2; ++nt) {
                const int base = (nt * 2) * 512 + lane * 8;
                const short8 Rh = *(const short8*)&pr[base];
                const short8 Rl = *(const short8*)&pr[base + 512];
                aR[nt] = MFMA(gh, Rh, aR[nt]);
                aR[nt] = MFMA(gh, Rl, aR[nt]);
                aR[nt] = MFMA(gl, Rh, aR[nt]);
            }
            #pragma unroll
            for (int nt = 0; nt < 2; ++nt)
                #pragma unroll
                for (int r = 0; r < 4; ++r) {
                    const int joE = tt * 16 + 4 * o + r;
                    if (joE < nOut) {
                        const int n = nl + 16 * nt;
                        ushort hh, hl;
                        split2(aR[nt][r], hh, hl);
                        HoH[joE * 40 + n] = hh;
                        HoL[joE * 40 + n] = hl;
                        if (l == 5 && joE < 2) {
                            const size_t go = ((size_t)b * 64 + cc * 2 + joE) * 32 + n;
                            c6h[go] = hh;
                            c6l[go] = hl;
                        }
                    }
                }
        }
        __syncthreads();
    }
}

// ---------------------------------------------------------------- fuseB tile
__device__ __forceinline__ void layer_tile1(
    const ushort* __restrict__ HiH, const ushort* __restrict__ HiL,
    ushort* __restrict__ HoH, ushort* __restrict__ HoL,
    const ushort* __restrict__ pd, const ushort* __restrict__ pr,
    const float* __restrict__ db, const float* __restrict__ rb,
    float* __restrict__ gout, ushort* __restrict__ sGH, ushort* __restrict__ sGL,
    int tt, int nIn, int nOut, int sO, int aO, int bOff,
    int lane, int nl, int o, int doRes)
{
    const short8 z8 = {0,0,0,0,0,0,0,0};
    const int joF = tt * 16 + nl;
    const int j0 = imin(2 * joF, nIn - 1);
    const int j1 = imin(2 * joF + 2, nIn - 1);
    const bool zB = (aO + joF * sO + bOff) > TLAST;

    float dbg[2], dbf[2], rbv[2];
    #pragma unroll
    for (int nt = 0; nt < 2; ++nt) {
        dbg[nt] = db[nl + 16 * nt];
        dbf[nt] = db[nl + 16 * nt + 32];
        rbv[nt] = rb[nl + 16 * nt];
    }

    // residual taps first
    f32x4 aR[2];
    #pragma unroll
    for (int nt = 0; nt < 2; ++nt)
        #pragma unroll
        for (int r = 0; r < 4; ++r) {
            const int joE = tt * 16 + 4 * o + r;
            const int jres = imin(2 * joE + 1, nIn - 1);
            const int n = nl + 16 * nt;
            aR[nt][r] = rbv[nt] + bf2f(HiH[jres * 40 + n]) +
                        bf2f(HiL[jres * 40 + n]);
        }

    short8 Ah[2], Al[2];
    Ah[0] = *(const short8*)&HiH[j0 * 40 + 8 * o];
    Al[0] = *(const short8*)&HiL[j0 * 40 + 8 * o];
    if (zB) { Ah[1] = z8; Al[1] = z8; }
    else {
        Ah[1] = *(const short8*)&HiH[j1 * 40 + 8 * o];
        Al[1] = *(const short8*)&HiL[j1 * 40 + 8 * o];
    }

    f32x4 acc[4];
    #pragma unroll
    for (int nt = 0; nt < 2; ++nt) {
        acc[nt]     = (f32x4){dbg[nt], dbg[nt], dbg[nt], dbg[nt]};
        acc[nt + 2] = (f32x4){dbf[nt], dbf[nt], dbf[nt], dbf[nt]};
    }
    #pragma unroll
    for (int kt = 0; kt < 2; ++kt)
        #pragma unroll
        for (int nt = 0; nt < 4; ++nt) {
            const int base = ((kt * 4 + nt) * 2) * 512 + lane * 8;
            const short8 Bh = *(const short8*)&pd[base];
            const short8 Bl = *(const short8*)&pd[base + 512];
            acc[nt] = MFMA(Ah[kt], Bh, acc[nt]);
            acc[nt] = MFMA(Ah[kt], Bl, acc[nt]);
            acc[nt] = MFMA(Al[kt], Bh, acc[nt]);
        }

    const int capRem = TLAST - aO;
    const int capIdx = ((capRem % sO) == 0) ? (capRem / sO) : -1;
    float gv[8];
    #pragma unroll
    for (int nt = 0; nt < 2; ++nt)
        #pragma unroll
        for (int r = 0; r < 4; ++r) {
            const float g = act_native(acc[nt][r], acc[nt + 2][r]);
            gv[nt * 4 + r] = g;
            const int ml = 4 * o + r, n = nl + 16 * nt;
            ushort gh16, gl16;
            split2(g, gh16, gl16);
            sGH[ml * 40 + n] = gh16;
            sGL[ml * 40 + n] = gl16;
        }
    if (capIdx >= tt * 16 && capIdx < imin(tt * 16 + 16, nOut)) {
        #pragma unroll
        for (int nt = 0; nt < 2; ++nt)
            #pragma unroll
            for (int r = 0; r < 4; ++r)
                if (tt * 16 + 4 * o + r == capIdx)
                    gout[nl + 16 * nt] = gv[nt * 4 + r];
    }

    if (doRes) {
        const short8 gh = *(const short8*)&sGH[nl * 40 + 8 * o];
        const short8 gl = *(const short8*)&sGL[nl * 40 + 8 * o];
        #pragma unroll
        for (int nt = 0; nt < 2; ++nt) {
            const int base = (nt * 2) * 512 + lane * 8;
            const short8 Rh = *(const short8*)&pr[base];
            const short8 Rl = *(const short8*)&pr[base + 512];
            aR[nt] = MFMA(gh, Rh, aR[nt]);
            aR[nt] = MFMA(gh, Rl, aR[nt]);
            aR[nt] = MFMA(gl, Rh, aR[nt]);
        }
        #pragma unroll
        for (int nt = 0; nt < 2; ++nt)
            #pragma unroll
            for (int r = 0; r < 4; ++r) {
                const int joE = tt * 16 + 4 * o + r;
                if (joE < nOut) {
                    const int n = nl + 16 * nt;
                    ushort hh, hl;
                    split2(aR[nt][r], hh, hl);
                    HoH[joE * 40 + n] = hh;
                    HoL[joE * 40 + n] = hl;
                }
            }
    }
}

// ---------------------------------------------------------------- phase B
__global__ __launch_bounds__(256) void wn_fuseB(
    const ushort* __restrict__ c6h, const ushort* __restrict__ c6l,
    const ushort* __restrict__ Wd, const ushort* __restrict__ Wr,
    const float* __restrict__ dil_b, const float* __restrict__ res_b,
    const float* __restrict__ gTL,
    const float* __restrict__ sw, const float* __restrict__ sb,
    const float* __restrict__ f1w, const float* __restrict__ f1b,
    const float* __restrict__ f2w, const float* __restrict__ f2b,
    float* __restrict__ out)
{
    __shared__ __align__(16) ushort HAh[64 * 40], HAl[64 * 40];
    __shared__ __align__(16) ushort HBh[32 * 40], HBl[32 * 40];
    __shared__ __align__(16) ushort sG2H[2][16 * 40], sG2L[2][16 * 40];
    __shared__ float gcap[6 * 32];
    __shared__ float psum[4][32];
    __shared__ float hd[64];

    const int tid = threadIdx.x, lane = tid & 63, w = tid >> 6;
    const int nl = lane & 15, o = lane >> 4;
    const int b = blockIdx.x;

    for (int i = tid; i < 256; i += 256) {
        const int row = i >> 2, c8 = (i & 3) * 8;
        *(short8*)&HAh[row * 40 + c8] = *(const short8*)&c6h[((size_t)b * 64 + row) * 32 + c8];
        *(short8*)&HAl[row * 40 + c8] = *(const short8*)&c6l[((size_t)b * 64 + row) * 32 + c8];
    }
    __syncthreads();

    if (w < 2) {
        layer_tile1(HAh, HAl, HBh, HBl, Wd + 6 * 8192, Wr + 6 * 2048,
                    dil_b + 6 * 64, res_b + 6 * 32,
                    gcap, sG2H[w], sG2L[w],
                    w, 64, 32, 64, 6206, 32, lane, nl, o, 1);
    }
    __syncthreads();

    if (w == 0) {
        for (int ll = 1; ll < 6; ++ll) {
            const int l = ll + 6;
            const ushort* HiH = (ll & 1) ? HBh : HAh;
            const ushort* HiL = (ll & 1) ? HBl : HAl;
            ushort* HoH = (ll & 1) ? HAh : HBh;
            ushort* HoL = (ll & 1) ? HAl : HBl;
            const int sO = 64 << ll;
            layer_tile1(HiH, HiL, HoH, HoL,
                        Wd + (size_t)l * 8192, Wr + (size_t)l * 2048,
                        dil_b + l * 64, res_b + l * 32,
                        gcap + ll * 32, sG2H[0], sG2L[0],
                        0, 64 >> ll, 32 >> ll, sO, 6142 + sO, sO >> 1,
                        lane, nl, o, (ll < 5) ? 1 : 0);
        }
    }
    __syncthreads();

    if (lane < 32) {
        const int c = lane;
        float part = 0.f;
        #pragma unroll
        for (int j = 0; j < 3; ++j) {
            const int l2 = 3 * w + j;
            float a = sb[l2 * 32 + c];
            const float* swr = sw + l2 * 1024 + c * 32;
            const float* gvp = (l2 < 6) ? (gTL + ((size_t)l2 * BATCH + b) * 32)
                                        : (gcap + (l2 - 6) * 32);
            #pragma unroll
            for (int ic = 0; ic < 32; ++ic) a += swr[ic] * gvp[ic];
            part += a;
        }
        psum[w][c] = part;
    }
    __syncthreads();

    if (w == 0 && lane < 32)
        hd[lane] = fmaxf(psum[0][lane] + psum[1][lane] + psum[2][lane] + psum[3][lane], 0.f);
    if (w == 0 && lane < 32) {
        float z = f1b[lane];
        #pragma unroll
        for (int ic = 0; ic < 32; ++ic) z += f1w[lane * 32 + ic] * hd[ic];
        hd[32 + lane] = fmaxf(z, 0.f);
    }
    if (w == 0 && lane == 0) {
        float o2 = f2b[0];
        #pragma unroll
        for (int ic = 0; ic < 32; ++ic) o2 += f2w[ic] * hd[32 + ic];
        out[b] = o2;
    }
}

// ---------------------------------------------------------------- launch
extern "C" void kernel_launch(void* const* d_in, const int* in_sizes, int n_in,
                              void* d_out, int out_size, void* d_ws, size_t ws_size,
                              hipStream_t stream)
{
    const float* x      = (const float*)d_in[0];
    const float* in_w   = (const float*)d_in[1];
    const float* in_b   = (const float*)d_in[2];
    const float* dil_w  = (const float*)d_in[3];
    const float* dil_b  = (const float*)d_in[4];
    const float* skip_w = (const float*)d_in[5];
    const float* skip_b = (const float*)d_in[6];
    const float* res_w  = (const float*)d_in[7];
    const float* res_b  = (const float*)d_in[8];
    const float* f1_w   = (const float*)d_in[9];
    const float* f1_b   = (const float*)d_in[10];
    const float* f2_w   = (const float*)d_in[11];
    const float* f2_b   = (const float*)d_in[12];

    char* p = (char*)d_ws;
    ushort* Wd  = (ushort*)p; p += 12 * 8192 * 2;
    ushort* Wr  = (ushort*)p; p += 12 * 2048 * 2;
    ushort* c6h = (ushort*)p; p += 32 * 64 * 32 * 2;
    ushort* c6l = (ushort*)p; p += 32 * 64 * 32 * 2;
    float*  gTL = (float*)p;

    wn_prep<<<dim3(240), dim3(256), 0, stream>>>(dil_w, res_w, Wd, Wr);

    wn_fuseA<<<dim3(32, BATCH), dim3(256), 0, stream>>>(
        x, in_w, in_b, Wd, Wr, dil_b, res_b, c6h, c6l, gTL);

    wn_fuseB<<<dim3(BATCH), dim3(256), 0, stream>>>(
        c6h, c6l, Wd, Wr, dil_b, res_b, gTL,
        skip_w, skip_b, f1_w, f1_b, f2_w, f2_b, (float*)d_out);
}